// Round 1
// baseline (1321.375 us; speedup 1.0000x reference)
//
#include <hip/hip_runtime.h>

// Problem constants
#define HW    50176            // 224*224
#define IMGW  224
#define SEG   196              // R*R = 14*14
#define NBATCH 128
#define NCOL  (NBATCH * SEG)   // 25088  (columns of every GEMM)
#define PB    16               // accumulation blocks per batch image
#define CHUNK (HW / PB)        // 3136 pixels per block

// ---------------------------------------------------------------------------
// Kernel 1: segmented accumulation.  stats layout: stats[f*NCOL + b*SEG + s]
// f: 0=count 1=row_sum 2=col_sum 3..5=rgb_sum 6..8=rgb_sq_sum
// ---------------------------------------------------------------------------
__global__ __launch_bounds__(256) void seg_accum(const float* __restrict__ x,
                                                 const int*   __restrict__ sl,
                                                 float*       __restrict__ stats) {
    __shared__ float ls[9][SEG];
    int b    = blockIdx.x / PB;
    int part = blockIdx.x % PB;
    int tid  = threadIdx.x;

    for (int i = tid; i < 9 * SEG; i += 256) (&ls[0][0])[i] = 0.f;
    __syncthreads();

    const float* xb = x + (size_t)b * 3 * HW;
    const int*   sb = sl + (size_t)b * HW;
    int p0 = part * CHUNK;
    for (int p = p0 + tid; p < p0 + CHUNK; p += 256) {
        int   id  = sb[p];
        float row = (float)(p / IMGW);
        float col = (float)(p % IMGW);
        float r  = xb[p];
        float g  = xb[HW + p];
        float bl = xb[2 * HW + p];
        atomicAdd(&ls[0][id], 1.f);
        atomicAdd(&ls[1][id], row);
        atomicAdd(&ls[2][id], col);
        atomicAdd(&ls[3][id], r);
        atomicAdd(&ls[4][id], g);
        atomicAdd(&ls[5][id], bl);
        atomicAdd(&ls[6][id], r * r);
        atomicAdd(&ls[7][id], g * g);
        atomicAdd(&ls[8][id], bl * bl);
    }
    __syncthreads();

    for (int i = tid; i < 9 * SEG; i += 256) {
        int f = i / SEG, s = i % SEG;
        float v = ls[f][s];
        if (v != 0.f) atomicAdd(&stats[(size_t)f * NCOL + (size_t)b * SEG + s], v);
    }
}

// ---------------------------------------------------------------------------
// Kernel 2: build 11 features per segment.  F layout: F[f*NCOL + n], n=b*SEG+s
// feature order: mean_row, mean_col, mean_rgb(3), std_rgb(3), gathered_rgb(3)
// ---------------------------------------------------------------------------
__global__ __launch_bounds__(256) void feat_build(const float* __restrict__ x,
                                                  const float* __restrict__ stats,
                                                  float*       __restrict__ F) {
    int n = blockIdx.x * 256 + threadIdx.x;
    if (n >= NCOL) return;
    int b = n / SEG;

    float cnt  = stats[n];
    float safe = fmaxf(cnt, 1.f);
    float inv  = 1.f / safe;
    float mrow = stats[1 * NCOL + n] * inv;
    float mcol = stats[2 * NCOL + n] * inv;
    float mr   = stats[3 * NCOL + n] * inv;
    float mg   = stats[4 * NCOL + n] * inv;
    float mb   = stats[5 * NCOL + n] * inv;
    float den  = fmaxf(cnt - 1.f, 1.f);
    float vr = (stats[6 * NCOL + n] - cnt * mr * mr) / den;
    float vg = (stats[7 * NCOL + n] - cnt * mg * mg) / den;
    float vb = (stats[8 * NCOL + n] - cnt * mb * mb) / den;
    bool  has2 = cnt > 1.f;
    float sr = has2 ? sqrtf(fmaxf(vr, 0.f)) : 0.f;
    float sg = has2 ? sqrtf(fmaxf(vg, 0.f)) : 0.f;
    float sb = has2 ? sqrtf(fmaxf(vb, 0.f)) : 0.f;

    int ri = min(max((int)mrow, 0), IMGW - 1);
    int ci = min(max((int)mcol, 0), IMGW - 1);
    const float* xb = x + (size_t)b * 3 * HW;
    int pi = ri * IMGW + ci;
    float gr = xb[pi], gg = xb[HW + pi], gb = xb[2 * HW + pi];

    float mask = cnt > 0.f ? 1.f : 0.f;
    F[0 * NCOL + n] = mrow * mask;
    F[1 * NCOL + n] = mcol * mask;
    F[2 * NCOL + n] = mr * mask;
    F[3 * NCOL + n] = mg * mask;
    F[4 * NCOL + n] = mb * mask;
    F[5 * NCOL + n] = sr * mask;
    F[6 * NCOL + n] = sg * mask;
    F[7 * NCOL + n] = sb * mask;
    F[8 * NCOL + n] = gr * mask;
    F[9 * NCOL + n] = gg * mask;
    F[10 * NCOL + n] = gb * mask;
}

// ---------------------------------------------------------------------------
// Kernel 3: fp32 GEMM + folded BN (+ReLU).  Out[o,n] = act(alpha[o]*sum_k W[o,k]*Hin[k,n] + beta[o])
// Tile 64(M)x64(N)x16(K), 256 threads, 4x4 micro-tile per thread.
// final_out: write in (b, 768, 196) layout instead of (M, NCOL).
// ---------------------------------------------------------------------------
__global__ __launch_bounds__(256) void gemm_bn(const float* __restrict__ Wt,
                                               const float* __restrict__ Hin,
                                               float*       __restrict__ Hout,
                                               const float* __restrict__ bias,
                                               const float* __restrict__ gam,
                                               const float* __restrict__ bet,
                                               const float* __restrict__ rm,
                                               const float* __restrict__ rv,
                                               int M, int K, int act, int final_out) {
    __shared__ float As[16][68];   // [k][m], padded: 16B-aligned rows, conflict-free
    __shared__ float Bs[16][64];   // [k][n]

    int tid = threadIdx.x;
    int tn = tid & 15;             // 0..15  -> 4 columns each
    int tm = tid >> 4;             // 0..15  -> 4 rows each
    int n0 = blockIdx.x * 64;
    int m0 = blockIdx.y * 64;

    float acc[4][4] = {{0.f}};

    int ktiles = (K + 15) / 16;
    for (int t = 0; t < ktiles; ++t) {
        int k0 = t * 16;
        // --- load W tile (64x16), thread -> row m=tid/4, 4 consecutive k ---
        {
            int m = tid >> 2;
            int kb = (tid & 3) * 4;
#pragma unroll
            for (int j = 0; j < 4; ++j) {
                int k = kb + j;
                float v = 0.f;
                int gm = m0 + m, gk = k0 + k;
                if (gm < M && gk < K) v = Wt[(size_t)gm * K + gk];
                As[k][m] = v;
            }
        }
        // --- load H tile (16x64) as float4 ---
        {
            int kk = tid >> 4;
            int nn = (tid & 15) * 4;
            float4 v = make_float4(0.f, 0.f, 0.f, 0.f);
            if (k0 + kk < K)
                v = *(const float4*)&Hin[(size_t)(k0 + kk) * NCOL + n0 + nn];
            *(float4*)&Bs[kk][nn] = v;
        }
        __syncthreads();
#pragma unroll
        for (int k = 0; k < 16; ++k) {
            float a[4], bb[4];
#pragma unroll
            for (int i = 0; i < 4; ++i) a[i] = As[k][tm * 4 + i];
#pragma unroll
            for (int j = 0; j < 4; ++j) bb[j] = Bs[k][tn * 4 + j];
#pragma unroll
            for (int i = 0; i < 4; ++i)
#pragma unroll
                for (int j = 0; j < 4; ++j) acc[i][j] += a[i] * bb[j];
        }
        __syncthreads();
    }

#pragma unroll
    for (int i = 0; i < 4; ++i) {
        int o = m0 + tm * 4 + i;
        if (o >= M) continue;
        float sc = gam[o] / sqrtf(rv[o] + 1e-5f);
        float al = sc;
        float bt = (bias[o] - rm[o]) * sc + bet[o];
#pragma unroll
        for (int j = 0; j < 4; ++j) {
            int n = n0 + tn * 4 + j;
            float v = acc[i][j] * al + bt;
            if (act) v = fmaxf(v, 0.f);
            if (final_out) {
                int b = n / SEG, s = n - b * SEG;
                Hout[(size_t)b * 768 * SEG + (size_t)o * SEG + s] = v;
            } else {
                Hout[(size_t)o * NCOL + n] = v;
            }
        }
    }
}

// ---------------------------------------------------------------------------
// Kernel 4: copy sliced (int32) -> out as float values
// ---------------------------------------------------------------------------
__global__ __launch_bounds__(256) void copy_sliced(const int4* __restrict__ sl,
                                                   float4* __restrict__ out) {
    int i = blockIdx.x * 256 + threadIdx.x;   // exactly 1605632 threads
    int4 v = sl[i];
    out[i] = make_float4((float)v.x, (float)v.y, (float)v.z, (float)v.w);
}

// ---------------------------------------------------------------------------
extern "C" void kernel_launch(void* const* d_in, const int* in_sizes, int n_in,
                              void* d_out, int out_size, void* d_ws, size_t ws_size,
                              hipStream_t stream) {
    const float* x  = (const float*)d_in[0];
    const int*   sl = (const int*)d_in[1];
    // layer params: d_in[2 + 6*i + {0:w,1:b,2:g,3:be,4:rm,5:rv}]
    const float* Wp[5], *Bp[5], *Gp[5], *BEp[5], *RMp[5], *RVp[5];
    for (int i = 0; i < 5; ++i) {
        Wp[i]  = (const float*)d_in[2 + 6 * i + 0];
        Bp[i]  = (const float*)d_in[2 + 6 * i + 1];
        Gp[i]  = (const float*)d_in[2 + 6 * i + 2];
        BEp[i] = (const float*)d_in[2 + 6 * i + 3];
        RMp[i] = (const float*)d_in[2 + 6 * i + 4];
        RVp[i] = (const float*)d_in[2 + 6 * i + 5];
    }
    float* out = (float*)d_out;

    // workspace layout (floats):
    //   stats:  9*NCOL
    //   F:     11*NCOL
    //   bufA: 384*NCOL   (holds L0 out 96, L2 out 384)
    //   bufB: 768*NCOL   (holds L1 out 192, L3 out 768)
    float* ws    = (float*)d_ws;
    float* stats = ws;
    float* F     = ws + (size_t)9 * NCOL;
    float* bufA  = ws + (size_t)20 * NCOL;
    float* bufB  = ws + (size_t)(20 + 384) * NCOL;

    hipMemsetAsync(stats, 0, (size_t)9 * NCOL * sizeof(float), stream);

    seg_accum<<<NBATCH * PB, 256, 0, stream>>>(x, sl, stats);
    feat_build<<<(NCOL + 255) / 256, 256, 0, stream>>>(x, stats, F);

    const int NT = NCOL / 64;  // 392 column tiles
    // L0: 11 -> 96, relu
    gemm_bn<<<dim3(NT, (96 + 63) / 64), 256, 0, stream>>>(
        Wp[0], F, bufA, Bp[0], Gp[0], BEp[0], RMp[0], RVp[0], 96, 11, 1, 0);
    // L1: 96 -> 192, relu
    gemm_bn<<<dim3(NT, (192 + 63) / 64), 256, 0, stream>>>(
        Wp[1], bufA, bufB, Bp[1], Gp[1], BEp[1], RMp[1], RVp[1], 192, 96, 1, 0);
    // L2: 192 -> 384, relu
    gemm_bn<<<dim3(NT, (384 + 63) / 64), 256, 0, stream>>>(
        Wp[2], bufB, bufA, Bp[2], Gp[2], BEp[2], RMp[2], RVp[2], 384, 192, 1, 0);
    // L3: 384 -> 768, relu
    gemm_bn<<<dim3(NT, (768 + 63) / 64), 256, 0, stream>>>(
        Wp[3], bufA, bufB, Bp[3], Gp[3], BEp[3], RMp[3], RVp[3], 768, 384, 1, 0);
    // L4: 768 -> 768, no act, write into d_out at offset B*H*W in (b,768,196) layout
    gemm_bn<<<dim3(NT, (768 + 63) / 64), 256, 0, stream>>>(
        Wp[4], bufB, out + (size_t)NBATCH * HW, Bp[4], Gp[4], BEp[4], RMp[4], RVp[4],
        768, 768, 0, 1);

    // output 0: sliced as float
    copy_sliced<<<(NBATCH * HW / 4) / 256, 256, 0, stream>>>((const int4*)sl,
                                                             (float4*)out);
}

// Round 2
// 690.975 us; speedup vs baseline: 1.9123x; 1.9123x over previous
//
#include <hip/hip_runtime.h>
#include <hip/hip_bf16.h>

// Problem constants
#define HW    50176            // 224*224
#define IMGW  224
#define SEG   196              // R*R
#define NBATCH 128
#define NCOL  (NBATCH * SEG)   // 25088 rows (pixels) of every GEMM
#define PB    16
#define CHUNK (HW / PB)

typedef __attribute__((ext_vector_type(8))) short bf16x8;   // 8 bf16 = 4 VGPRs
typedef __attribute__((ext_vector_type(4))) float f32x4;

static __device__ __forceinline__ ushort f2bf(float v) {
    __hip_bfloat16 h = __float2bfloat16(v);
    return *reinterpret_cast<ushort*>(&h);
}

// ---------------------------------------------------------------------------
// Kernel 1: segmented accumulation (fp32, LDS atomics).
// stats[f*NCOL + b*SEG + s], f: 0=cnt 1=rowsum 2=colsum 3..5=rgb 6..8=rgb^2
// ---------------------------------------------------------------------------
__global__ __launch_bounds__(256) void seg_accum(const float* __restrict__ x,
                                                 const int*   __restrict__ sl,
                                                 float*       __restrict__ stats) {
    __shared__ float ls[9][SEG];
    int b    = blockIdx.x / PB;
    int part = blockIdx.x % PB;
    int tid  = threadIdx.x;

    for (int i = tid; i < 9 * SEG; i += 256) (&ls[0][0])[i] = 0.f;
    __syncthreads();

    const float* xb = x + (size_t)b * 3 * HW;
    const int*   sb = sl + (size_t)b * HW;
    int p0 = part * CHUNK;
    for (int p = p0 + tid; p < p0 + CHUNK; p += 256) {
        int   id  = sb[p];
        float row = (float)(p / IMGW);
        float col = (float)(p % IMGW);
        float r  = xb[p];
        float g  = xb[HW + p];
        float bl = xb[2 * HW + p];
        atomicAdd(&ls[0][id], 1.f);
        atomicAdd(&ls[1][id], row);
        atomicAdd(&ls[2][id], col);
        atomicAdd(&ls[3][id], r);
        atomicAdd(&ls[4][id], g);
        atomicAdd(&ls[5][id], bl);
        atomicAdd(&ls[6][id], r * r);
        atomicAdd(&ls[7][id], g * g);
        atomicAdd(&ls[8][id], bl * bl);
    }
    __syncthreads();

    for (int i = tid; i < 9 * SEG; i += 256) {
        int f = i / SEG, s = i % SEG;
        float v = ls[f][s];
        if (v != 0.f) atomicAdd(&stats[(size_t)f * NCOL + (size_t)b * SEG + s], v);
    }
}

// ---------------------------------------------------------------------------
// Kernel 2: 11 features -> bf16 F[n][64] (cols 11..63 zero). n = b*SEG+s.
// ---------------------------------------------------------------------------
__global__ __launch_bounds__(256) void feat_build(const float* __restrict__ x,
                                                  const float* __restrict__ stats,
                                                  ushort*      __restrict__ F) {
    int n = blockIdx.x * 256 + threadIdx.x;
    if (n >= NCOL) return;
    int b = n / SEG;

    float cnt  = stats[n];
    float safe = fmaxf(cnt, 1.f);
    float inv  = 1.f / safe;
    float mrow = stats[1 * NCOL + n] * inv;
    float mcol = stats[2 * NCOL + n] * inv;
    float mr   = stats[3 * NCOL + n] * inv;
    float mg   = stats[4 * NCOL + n] * inv;
    float mb   = stats[5 * NCOL + n] * inv;
    float den  = fmaxf(cnt - 1.f, 1.f);
    float vr = (stats[6 * NCOL + n] - cnt * mr * mr) / den;
    float vg = (stats[7 * NCOL + n] - cnt * mg * mg) / den;
    float vb = (stats[8 * NCOL + n] - cnt * mb * mb) / den;
    bool  has2 = cnt > 1.f;
    float sr = has2 ? sqrtf(fmaxf(vr, 0.f)) : 0.f;
    float sg = has2 ? sqrtf(fmaxf(vg, 0.f)) : 0.f;
    float sb = has2 ? sqrtf(fmaxf(vb, 0.f)) : 0.f;

    int ri = min(max((int)mrow, 0), IMGW - 1);
    int ci = min(max((int)mcol, 0), IMGW - 1);
    const float* xb = x + (size_t)b * 3 * HW;
    int pi = ri * IMGW + ci;
    float gr = xb[pi], gg = xb[HW + pi], gb = xb[2 * HW + pi];

    float mask = cnt > 0.f ? 1.f : 0.f;
    ushort* Fr = F + (size_t)n * 64;
    Fr[0]  = f2bf(mrow * mask);
    Fr[1]  = f2bf(mcol * mask);
    Fr[2]  = f2bf(mr * mask);
    Fr[3]  = f2bf(mg * mask);
    Fr[4]  = f2bf(mb * mask);
    Fr[5]  = f2bf(sr * mask);
    Fr[6]  = f2bf(sg * mask);
    Fr[7]  = f2bf(sb * mask);
    Fr[8]  = f2bf(gr * mask);
    Fr[9]  = f2bf(gg * mask);
    Fr[10] = f2bf(gb * mask);
#pragma unroll
    for (int k = 11; k < 64; ++k) Fr[k] = 0;
}

// ---------------------------------------------------------------------------
// Kernel 3: weight convert fp32 (Cout,K) -> bf16 padded (Opad,Kpad), zero pads
// ---------------------------------------------------------------------------
__global__ __launch_bounds__(256) void convert_w(const float* __restrict__ src,
                                                 ushort* __restrict__ dst,
                                                 int Cout, int K, int Kpad, int total) {
    int i = blockIdx.x * 256 + threadIdx.x;
    if (i >= total) return;
    int o = i / Kpad, k = i - o * Kpad;
    float v = (o < Cout && k < K) ? src[(size_t)o * K + k] : 0.f;
    dst[i] = f2bf(v);
}

// ---------------------------------------------------------------------------
// Kernel 4: bf16 MFMA GEMM (m97 structure) + folded BN (+ReLU).
// C[n][o] = act(alpha[o] * sum_k Aact[n][k]*Wb[o][k] + beta[o])
// Block 128(n) x 128(o), BK=64, 4 waves in 2x2, 4x4 16x16x32 frags per wave.
// intermediate out: bf16 [n][OutStride]; final out: fp32 (b, 768, SEG).
// ---------------------------------------------------------------------------
__global__ __launch_bounds__(256) void gemm_mfma(const ushort* __restrict__ Aact,
                                                 const ushort* __restrict__ Wb,
                                                 void* __restrict__ outp,
                                                 const float* __restrict__ bias,
                                                 const float* __restrict__ gam,
                                                 const float* __restrict__ bet,
                                                 const float* __restrict__ rm,
                                                 const float* __restrict__ rv,
                                                 int Kpad, int Cout, int OutStride,
                                                 int act, int final_out) {
    __shared__ ushort As[128 * 64];   // [n][k]
    __shared__ ushort Bs[128 * 64];   // [o][k]

    int tid  = threadIdx.x;
    int lane = tid & 63;
    int wid  = tid >> 6;
    int wm   = wid & 1;               // wave row (n)
    int wn   = wid >> 1;              // wave col (o)
    int n0   = blockIdx.x * 128;
    int o0   = blockIdx.y * 128;
    int mrow = lane & 15;
    int quad = lane >> 4;

    f32x4 acc[4][4];
#pragma unroll
    for (int i = 0; i < 4; ++i)
#pragma unroll
        for (int j = 0; j < 4; ++j) acc[i][j] = (f32x4){0.f, 0.f, 0.f, 0.f};

    int ktiles = Kpad >> 6;
    for (int kt = 0; kt < ktiles; ++kt) {
        int kb = kt * 64;
        // stage A tile: 128 rows x 64 k, 16B per lane, 4 passes
#pragma unroll
        for (int p = 0; p < 4; ++p) {
            int flat = p * 256 + tid;
            int row = flat >> 3, kg = flat & 7;
            const ushort* gp = Aact + (size_t)(n0 + row) * Kpad + kb + kg * 8;
            __builtin_amdgcn_global_load_lds(
                (const __attribute__((address_space(1))) void*)gp,
                (__attribute__((address_space(3))) void*)(As + (size_t)(p * 256 + wid * 64) * 8),
                16, 0, 0);
        }
        // stage B tile (weights)
#pragma unroll
        for (int p = 0; p < 4; ++p) {
            int flat = p * 256 + tid;
            int row = flat >> 3, kg = flat & 7;
            const ushort* gp = Wb + (size_t)(o0 + row) * Kpad + kb + kg * 8;
            __builtin_amdgcn_global_load_lds(
                (const __attribute__((address_space(1))) void*)gp,
                (__attribute__((address_space(3))) void*)(Bs + (size_t)(p * 256 + wid * 64) * 8),
                16, 0, 0);
        }
        __syncthreads();

#pragma unroll
        for (int ks = 0; ks < 2; ++ks) {
            bf16x8 af[4], bfr[4];
#pragma unroll
            for (int i = 0; i < 4; ++i)
                af[i] = *(const bf16x8*)&As[(size_t)(wm * 64 + i * 16 + mrow) * 64 + ks * 32 + quad * 8];
#pragma unroll
            for (int j = 0; j < 4; ++j)
                bfr[j] = *(const bf16x8*)&Bs[(size_t)(wn * 64 + j * 16 + mrow) * 64 + ks * 32 + quad * 8];
#pragma unroll
            for (int i = 0; i < 4; ++i)
#pragma unroll
                for (int j = 0; j < 4; ++j)
                    acc[i][j] = __builtin_amdgcn_mfma_f32_16x16x32_bf16(af[i], bfr[j], acc[i][j], 0, 0, 0);
        }
        __syncthreads();
    }

    // epilogue: C row = n (quad*4+reg), col = o (lane&15)
#pragma unroll
    for (int j = 0; j < 4; ++j) {
        int o = o0 + wn * 64 + j * 16 + mrow;
        float al = 0.f, bt = 0.f;
        if (o < Cout) {
            float sc = gam[o] / sqrtf(rv[o] + 1e-5f);
            al = sc;
            bt = (bias[o] - rm[o]) * sc + bet[o];
        }
#pragma unroll
        for (int i = 0; i < 4; ++i) {
            int nbase = n0 + wm * 64 + i * 16 + quad * 4;
#pragma unroll
            for (int r = 0; r < 4; ++r) {
                float v = acc[i][j][r] * al + bt;
                if (act) v = fmaxf(v, 0.f);
                int n = nbase + r;
                if (final_out) {
                    int b = n / SEG, s = n - b * SEG;
                    ((float*)outp)[(size_t)b * 768 * SEG + (size_t)o * SEG + s] = v;
                } else {
                    ((ushort*)outp)[(size_t)n * OutStride + o] = f2bf(v);
                }
            }
        }
    }
}

// ---------------------------------------------------------------------------
// Kernel 5: copy sliced (int32) -> out as float values
// ---------------------------------------------------------------------------
__global__ __launch_bounds__(256) void copy_sliced(const int4* __restrict__ sl,
                                                   float4* __restrict__ out) {
    int i = blockIdx.x * 256 + threadIdx.x;
    int4 v = sl[i];
    out[i] = make_float4((float)v.x, (float)v.y, (float)v.z, (float)v.w);
}

// ---------------------------------------------------------------------------
extern "C" void kernel_launch(void* const* d_in, const int* in_sizes, int n_in,
                              void* d_out, int out_size, void* d_ws, size_t ws_size,
                              hipStream_t stream) {
    const float* x  = (const float*)d_in[0];
    const int*   sl = (const int*)d_in[1];
    const float* Wp[5], *Bp[5], *Gp[5], *BEp[5], *RMp[5], *RVp[5];
    for (int i = 0; i < 5; ++i) {
        Wp[i]  = (const float*)d_in[2 + 6 * i + 0];
        Bp[i]  = (const float*)d_in[2 + 6 * i + 1];
        Gp[i]  = (const float*)d_in[2 + 6 * i + 2];
        BEp[i] = (const float*)d_in[2 + 6 * i + 3];
        RMp[i] = (const float*)d_in[2 + 6 * i + 4];
        RVp[i] = (const float*)d_in[2 + 6 * i + 5];
    }
    float* out = (float*)d_out;

    // layer geometry: K (=prev Opad), Kreal, Cout, Opad
    const int Kpad[5]  = {64, 128, 256, 384, 768};
    const int Kreal[5] = {11, 96, 192, 384, 768};
    const int Cout[5]  = {96, 192, 384, 768, 768};
    const int Opad[5]  = {128, 256, 384, 768, 768};

    // workspace layout
    char* wsb = (char*)d_ws;
    float*  stats = (float*)wsb;                        // 9*NCOL fp32
    wsb += (size_t)9 * NCOL * sizeof(float);
    ushort* F = (ushort*)wsb;                           // NCOL x 64 bf16
    wsb += (size_t)NCOL * 64 * sizeof(ushort);
    ushort* Wpad[5];
    for (int i = 0; i < 5; ++i) {
        Wpad[i] = (ushort*)wsb;
        wsb += (size_t)Opad[i] * Kpad[i] * sizeof(ushort);
    }
    ushort* bufA = (ushort*)wsb;                        // NCOL x 384 bf16 max
    wsb += (size_t)NCOL * 384 * sizeof(ushort);
    ushort* bufB = (ushort*)wsb;                        // NCOL x 768 bf16

    hipMemsetAsync(stats, 0, (size_t)9 * NCOL * sizeof(float), stream);

    for (int i = 0; i < 5; ++i) {
        int total = Opad[i] * Kpad[i];
        convert_w<<<(total + 255) / 256, 256, 0, stream>>>(
            Wp[i], Wpad[i], Cout[i], Kreal[i], Kpad[i], total);
    }

    seg_accum<<<NBATCH * PB, 256, 0, stream>>>(x, sl, stats);
    feat_build<<<(NCOL + 255) / 256, 256, 0, stream>>>(x, stats, F);

    const int NT = NCOL / 128;  // 196 row tiles
    // L0: 11(64) -> 96(128), relu
    gemm_mfma<<<dim3(NT, Opad[0] / 128), 256, 0, stream>>>(
        F, Wpad[0], bufA, Bp[0], Gp[0], BEp[0], RMp[0], RVp[0],
        Kpad[0], Cout[0], Opad[0], 1, 0);
    // L1: 96(128) -> 192(256), relu
    gemm_mfma<<<dim3(NT, Opad[1] / 128), 256, 0, stream>>>(
        bufA, Wpad[1], bufB, Bp[1], Gp[1], BEp[1], RMp[1], RVp[1],
        Kpad[1], Cout[1], Opad[1], 1, 0);
    // L2: 192(256) -> 384, relu
    gemm_mfma<<<dim3(NT, Opad[2] / 128), 256, 0, stream>>>(
        bufB, Wpad[2], bufA, Bp[2], Gp[2], BEp[2], RMp[2], RVp[2],
        Kpad[2], Cout[2], Opad[2], 1, 0);
    // L3: 384 -> 768, relu
    gemm_mfma<<<dim3(NT, Opad[3] / 128), 256, 0, stream>>>(
        bufA, Wpad[3], bufB, Bp[3], Gp[3], BEp[3], RMp[3], RVp[3],
        Kpad[3], Cout[3], Opad[3], 1, 0);
    // L4: 768 -> 768, no act, fp32 out at offset B*H*W in (b,768,196) layout
    gemm_mfma<<<dim3(NT, Opad[4] / 128), 256, 0, stream>>>(
        bufB, Wpad[4], out + (size_t)NBATCH * HW, Bp[4], Gp[4], BEp[4], RMp[4], RVp[4],
        Kpad[4], Cout[4], 0, 0, 1);

    // output 0: sliced as float
    copy_sliced<<<(NBATCH * HW / 4) / 256, 256, 0, stream>>>((const int4*)sl,
                                                             (float4*)out);
}

// Round 3
// 442.280 us; speedup vs baseline: 2.9876x; 1.5623x over previous
//
#include <hip/hip_runtime.h>
#include <hip/hip_bf16.h>

// Problem constants
#define HW    50176            // 224*224
#define IMGW  224
#define SEG   196              // R*R
#define NBATCH 128
#define NCOL  (NBATCH * SEG)   // 25088 rows (pixels) of every GEMM
#define PB    14               // accumulation blocks per batch image
#define CHUNK (HW / PB)        // 3584 pixels per block
#define VCHUNK (CHUNK / 4)     // 896 float4 groups per block

typedef __attribute__((ext_vector_type(8))) short bf16x8;   // 8 bf16 = 4 VGPRs
typedef __attribute__((ext_vector_type(4))) float f32x4;
typedef unsigned long long u64;

static __device__ __forceinline__ ushort f2bf(float v) {
    __hip_bfloat16 h = __float2bfloat16(v);
    return *reinterpret_cast<ushort*>(&h);
}

// ---------------------------------------------------------------------------
// Kernel 1: segmented accumulation via packed u64 LDS atomics (4 per pixel).
//  ls0: count<<48 | rowsum<<24 | colsum      (exact integers)
//  ls1: qg<<32 | qr      q(v) = round((v+16)*8192)   (bias removed at flush)
//  ls2: qr2<<32 | qb     q2(v) = round(v*v*2048)
//  ls3: qb2<<32 | qg2
// Flush decodes to fp32 and atomically adds into stats[f*NCOL + b*SEG + s],
// f: 0=cnt 1=rowsum 2=colsum 3..5=rgb 6..8=rgb^2  (same layout as before).
// Field bounds (CHUNK=3584): cnt<2^16; rowsum<=3584*223=0.8M<2^24;
// rgb field <= 3584*32*8192 = 9.4e8 < 2^32; sq field <= 3584*256*2048=1.88e9.
// ---------------------------------------------------------------------------
__global__ __launch_bounds__(256) void seg_accum(const float* __restrict__ x,
                                                 const int*   __restrict__ sl,
                                                 float*       __restrict__ stats) {
    __shared__ u64 ls[4][SEG];
    int b    = blockIdx.x / PB;
    int part = blockIdx.x % PB;
    int tid  = threadIdx.x;

    for (int i = tid; i < 4 * SEG; i += 256) (&ls[0][0])[i] = 0ull;
    __syncthreads();

    const float* xb = x + (size_t)b * 3 * HW;
    const int*   sb = sl + (size_t)b * HW;
    int v0 = part * VCHUNK;

    for (int vi = tid; vi < VCHUNK; vi += 256) {
        int vg = v0 + vi;                 // float4 group index in image
        int4   id4 = ((const int4*)sb)[vg];
        float4 r4  = ((const float4*)xb)[vg];
        float4 g4  = ((const float4*)(xb + HW))[vg];
        float4 b4  = ((const float4*)(xb + 2 * HW))[vg];
        int p   = vg * 4;
        int row = p / IMGW;               // 4 | 224 -> all 4 pixels same row
        int col = p - row * IMGW;
        u64 rowbits = ((u64)1 << 48) | ((u64)(unsigned)row << 24);

#pragma unroll
        for (int q = 0; q < 4; ++q) {
            int   id = (q == 0) ? id4.x : (q == 1) ? id4.y : (q == 2) ? id4.z : id4.w;
            float r  = (q == 0) ? r4.x  : (q == 1) ? r4.y  : (q == 2) ? r4.z  : r4.w;
            float g  = (q == 0) ? g4.x  : (q == 1) ? g4.y  : (q == 2) ? g4.z  : g4.w;
            float bl = (q == 0) ? b4.x  : (q == 1) ? b4.y  : (q == 2) ? b4.z  : b4.w;

            unsigned qr  = (unsigned)fmaf(r,  8192.f, 131072.5f);   // (r+16)*8192
            unsigned qg  = (unsigned)fmaf(g,  8192.f, 131072.5f);
            unsigned qb  = (unsigned)fmaf(bl, 8192.f, 131072.5f);
            unsigned qr2 = (unsigned)fmaf(r * r,  2048.f, 0.5f);
            unsigned qg2 = (unsigned)fmaf(g * g,  2048.f, 0.5f);
            unsigned qb2 = (unsigned)fmaf(bl * bl, 2048.f, 0.5f);

            atomicAdd(&ls[0][id], rowbits | (unsigned)(col + q));
            atomicAdd(&ls[1][id], ((u64)qg  << 32) | qr);
            atomicAdd(&ls[2][id], ((u64)qr2 << 32) | qb);
            atomicAdd(&ls[3][id], ((u64)qb2 << 32) | qg2);
        }
    }
    __syncthreads();

    const float inv_s = 1.f / 8192.f, inv_q = 1.f / 2048.f;
    for (int i = tid; i < SEG; i += 256) {
        u64 v0p = ls[0][i];
        unsigned cnt = (unsigned)(v0p >> 48);
        if (!cnt) continue;
        float fc   = (float)cnt;
        float rows = (float)((unsigned)(v0p >> 24) & 0xFFFFFFu);
        float cols = (float)((unsigned)v0p & 0xFFFFFFu);
        u64 v1 = ls[1][i], v2 = ls[2][i], v3 = ls[3][i];
        float bias = 16.f * fc;
        float rsum = (float)(unsigned)v1         * inv_s - bias;
        float gsum = (float)(unsigned)(v1 >> 32) * inv_s - bias;
        float bsum = (float)(unsigned)v2         * inv_s - bias;
        float rsq  = (float)(unsigned)(v2 >> 32) * inv_q;
        float gsq  = (float)(unsigned)v3         * inv_q;
        float bsq  = (float)(unsigned)(v3 >> 32) * inv_q;

        size_t base = (size_t)b * SEG + i;
        atomicAdd(&stats[0 * NCOL + base], fc);
        atomicAdd(&stats[1 * NCOL + base], rows);
        atomicAdd(&stats[2 * NCOL + base], cols);
        atomicAdd(&stats[3 * NCOL + base], rsum);
        atomicAdd(&stats[4 * NCOL + base], gsum);
        atomicAdd(&stats[5 * NCOL + base], bsum);
        atomicAdd(&stats[6 * NCOL + base], rsq);
        atomicAdd(&stats[7 * NCOL + base], gsq);
        atomicAdd(&stats[8 * NCOL + base], bsq);
    }
}

// ---------------------------------------------------------------------------
// Kernel 2: 11 features -> bf16 F[n][64] (cols 11..63 zero). n = b*SEG+s.
// ---------------------------------------------------------------------------
__global__ __launch_bounds__(256) void feat_build(const float* __restrict__ x,
                                                  const float* __restrict__ stats,
                                                  ushort*      __restrict__ F) {
    int n = blockIdx.x * 256 + threadIdx.x;
    if (n >= NCOL) return;
    int b = n / SEG;

    float cnt  = stats[n];
    float safe = fmaxf(cnt, 1.f);
    float inv  = 1.f / safe;
    float mrow = stats[1 * NCOL + n] * inv;
    float mcol = stats[2 * NCOL + n] * inv;
    float mr   = stats[3 * NCOL + n] * inv;
    float mg   = stats[4 * NCOL + n] * inv;
    float mb   = stats[5 * NCOL + n] * inv;
    float den  = fmaxf(cnt - 1.f, 1.f);
    float vr = (stats[6 * NCOL + n] - cnt * mr * mr) / den;
    float vg = (stats[7 * NCOL + n] - cnt * mg * mg) / den;
    float vb = (stats[8 * NCOL + n] - cnt * mb * mb) / den;
    bool  has2 = cnt > 1.f;
    float sr = has2 ? sqrtf(fmaxf(vr, 0.f)) : 0.f;
    float sg = has2 ? sqrtf(fmaxf(vg, 0.f)) : 0.f;
    float sb = has2 ? sqrtf(fmaxf(vb, 0.f)) : 0.f;

    int ri = min(max((int)mrow, 0), IMGW - 1);
    int ci = min(max((int)mcol, 0), IMGW - 1);
    const float* xb = x + (size_t)b * 3 * HW;
    int pi = ri * IMGW + ci;
    float gr = xb[pi], gg = xb[HW + pi], gb = xb[2 * HW + pi];

    float mask = cnt > 0.f ? 1.f : 0.f;
    ushort* Fr = F + (size_t)n * 64;
    Fr[0]  = f2bf(mrow * mask);
    Fr[1]  = f2bf(mcol * mask);
    Fr[2]  = f2bf(mr * mask);
    Fr[3]  = f2bf(mg * mask);
    Fr[4]  = f2bf(mb * mask);
    Fr[5]  = f2bf(sr * mask);
    Fr[6]  = f2bf(sg * mask);
    Fr[7]  = f2bf(sb * mask);
    Fr[8]  = f2bf(gr * mask);
    Fr[9]  = f2bf(gg * mask);
    Fr[10] = f2bf(gb * mask);
#pragma unroll
    for (int k = 11; k < 64; ++k) Fr[k] = 0;
}

// ---------------------------------------------------------------------------
// Kernel 3: weight convert fp32 (Cout,K) -> bf16 padded (Opad,Kpad), zero pads
// ---------------------------------------------------------------------------
__global__ __launch_bounds__(256) void convert_w(const float* __restrict__ src,
                                                 ushort* __restrict__ dst,
                                                 int Cout, int K, int Kpad, int total) {
    int i = blockIdx.x * 256 + threadIdx.x;
    if (i >= total) return;
    int o = i / Kpad, k = i - o * Kpad;
    float v = (o < Cout && k < K) ? src[(size_t)o * K + k] : 0.f;
    dst[i] = f2bf(v);
}

// ---------------------------------------------------------------------------
// Kernel 4: bf16 MFMA GEMM (m97 structure) + folded BN (+ReLU).
// C[n][o] = act(alpha[o] * sum_k Aact[n][k]*Wb[o][k] + beta[o])
// Block 128(n) x 128(o), BK=64, 4 waves in 2x2, 4x4 16x16x32 frags per wave.
// intermediate out: bf16 [n][OutStride]; final out: fp32 (b, 768, SEG).
// ---------------------------------------------------------------------------
__global__ __launch_bounds__(256) void gemm_mfma(const ushort* __restrict__ Aact,
                                                 const ushort* __restrict__ Wb,
                                                 void* __restrict__ outp,
                                                 const float* __restrict__ bias,
                                                 const float* __restrict__ gam,
                                                 const float* __restrict__ bet,
                                                 const float* __restrict__ rm,
                                                 const float* __restrict__ rv,
                                                 int Kpad, int Cout, int OutStride,
                                                 int act, int final_out) {
    __shared__ ushort As[128 * 64];   // [n][k]
    __shared__ ushort Bs[128 * 64];   // [o][k]

    int tid  = threadIdx.x;
    int lane = tid & 63;
    int wid  = tid >> 6;
    int wm   = wid & 1;               // wave row (n)
    int wn   = wid >> 1;              // wave col (o)
    int n0   = blockIdx.x * 128;
    int o0   = blockIdx.y * 128;
    int mrow = lane & 15;
    int quad = lane >> 4;

    f32x4 acc[4][4];
#pragma unroll
    for (int i = 0; i < 4; ++i)
#pragma unroll
        for (int j = 0; j < 4; ++j) acc[i][j] = (f32x4){0.f, 0.f, 0.f, 0.f};

    int ktiles = Kpad >> 6;
    for (int kt = 0; kt < ktiles; ++kt) {
        int kb = kt * 64;
        // stage A tile: 128 rows x 64 k, 16B per lane, 4 passes
#pragma unroll
        for (int p = 0; p < 4; ++p) {
            int flat = p * 256 + tid;
            int row = flat >> 3, kg = flat & 7;
            const ushort* gp = Aact + (size_t)(n0 + row) * Kpad + kb + kg * 8;
            __builtin_amdgcn_global_load_lds(
                (const __attribute__((address_space(1))) void*)gp,
                (__attribute__((address_space(3))) void*)(As + (size_t)(p * 256 + wid * 64) * 8),
                16, 0, 0);
        }
        // stage B tile (weights)
#pragma unroll
        for (int p = 0; p < 4; ++p) {
            int flat = p * 256 + tid;
            int row = flat >> 3, kg = flat & 7;
            const ushort* gp = Wb + (size_t)(o0 + row) * Kpad + kb + kg * 8;
            __builtin_amdgcn_global_load_lds(
                (const __attribute__((address_space(1))) void*)gp,
                (__attribute__((address_space(3))) void*)(Bs + (size_t)(p * 256 + wid * 64) * 8),
                16, 0, 0);
        }
        __syncthreads();

#pragma unroll
        for (int ks = 0; ks < 2; ++ks) {
            bf16x8 af[4], bfr[4];
#pragma unroll
            for (int i = 0; i < 4; ++i)
                af[i] = *(const bf16x8*)&As[(size_t)(wm * 64 + i * 16 + mrow) * 64 + ks * 32 + quad * 8];
#pragma unroll
            for (int j = 0; j < 4; ++j)
                bfr[j] = *(const bf16x8*)&Bs[(size_t)(wn * 64 + j * 16 + mrow) * 64 + ks * 32 + quad * 8];
#pragma unroll
            for (int i = 0; i < 4; ++i)
#pragma unroll
                for (int j = 0; j < 4; ++j)
                    acc[i][j] = __builtin_amdgcn_mfma_f32_16x16x32_bf16(af[i], bfr[j], acc[i][j], 0, 0, 0);
        }
        __syncthreads();
    }

    // epilogue: C row = n (quad*4+reg), col = o (lane&15)
#pragma unroll
    for (int j = 0; j < 4; ++j) {
        int o = o0 + wn * 64 + j * 16 + mrow;
        float al = 0.f, bt = 0.f;
        if (o < Cout) {
            float sc = gam[o] / sqrtf(rv[o] + 1e-5f);
            al = sc;
            bt = (bias[o] - rm[o]) * sc + bet[o];
        }
#pragma unroll
        for (int i = 0; i < 4; ++i) {
            int nbase = n0 + wm * 64 + i * 16 + quad * 4;
#pragma unroll
            for (int r = 0; r < 4; ++r) {
                float v = acc[i][j][r] * al + bt;
                if (act) v = fmaxf(v, 0.f);
                int n = nbase + r;
                if (final_out) {
                    int b = n / SEG, s = n - b * SEG;
                    ((float*)outp)[(size_t)b * 768 * SEG + (size_t)o * SEG + s] = v;
                } else {
                    ((ushort*)outp)[(size_t)n * OutStride + o] = f2bf(v);
                }
            }
        }
    }
}

// ---------------------------------------------------------------------------
// Kernel 5: copy sliced (int32) -> out as float values
// ---------------------------------------------------------------------------
__global__ __launch_bounds__(256) void copy_sliced(const int4* __restrict__ sl,
                                                   float4* __restrict__ out) {
    int i = blockIdx.x * 256 + threadIdx.x;
    int4 v = sl[i];
    out[i] = make_float4((float)v.x, (float)v.y, (float)v.z, (float)v.w);
}

// ---------------------------------------------------------------------------
extern "C" void kernel_launch(void* const* d_in, const int* in_sizes, int n_in,
                              void* d_out, int out_size, void* d_ws, size_t ws_size,
                              hipStream_t stream) {
    const float* x  = (const float*)d_in[0];
    const int*   sl = (const int*)d_in[1];
    const float* Wp[5], *Bp[5], *Gp[5], *BEp[5], *RMp[5], *RVp[5];
    for (int i = 0; i < 5; ++i) {
        Wp[i]  = (const float*)d_in[2 + 6 * i + 0];
        Bp[i]  = (const float*)d_in[2 + 6 * i + 1];
        Gp[i]  = (const float*)d_in[2 + 6 * i + 2];
        BEp[i] = (const float*)d_in[2 + 6 * i + 3];
        RMp[i] = (const float*)d_in[2 + 6 * i + 4];
        RVp[i] = (const float*)d_in[2 + 6 * i + 5];
    }
    float* out = (float*)d_out;

    // layer geometry: Kpad (=prev Opad), Kreal, Cout, Opad
    const int Kpad[5]  = {64, 128, 256, 384, 768};
    const int Kreal[5] = {11, 96, 192, 384, 768};
    const int Cout[5]  = {96, 192, 384, 768, 768};
    const int Opad[5]  = {128, 256, 384, 768, 768};

    // workspace layout
    char* wsb = (char*)d_ws;
    float*  stats = (float*)wsb;                        // 9*NCOL fp32
    wsb += (size_t)9 * NCOL * sizeof(float);
    ushort* F = (ushort*)wsb;                           // NCOL x 64 bf16
    wsb += (size_t)NCOL * 64 * sizeof(ushort);
    ushort* Wpad[5];
    for (int i = 0; i < 5; ++i) {
        Wpad[i] = (ushort*)wsb;
        wsb += (size_t)Opad[i] * Kpad[i] * sizeof(ushort);
    }
    ushort* bufA = (ushort*)wsb;                        // NCOL x 384 bf16 max
    wsb += (size_t)NCOL * 384 * sizeof(ushort);
    ushort* bufB = (ushort*)wsb;                        // NCOL x 768 bf16

    hipMemsetAsync(stats, 0, (size_t)9 * NCOL * sizeof(float), stream);

    for (int i = 0; i < 5; ++i) {
        int total = Opad[i] * Kpad[i];
        convert_w<<<(total + 255) / 256, 256, 0, stream>>>(
            Wp[i], Wpad[i], Cout[i], Kreal[i], Kpad[i], total);
    }

    seg_accum<<<NBATCH * PB, 256, 0, stream>>>(x, sl, stats);
    feat_build<<<(NCOL + 255) / 256, 256, 0, stream>>>(x, stats, F);

    const int NT = NCOL / 128;  // 196 row tiles
    // L0: 11(64) -> 96(128), relu
    gemm_mfma<<<dim3(NT, Opad[0] / 128), 256, 0, stream>>>(
        F, Wpad[0], bufA, Bp[0], Gp[0], BEp[0], RMp[0], RVp[0],
        Kpad[0], Cout[0], Opad[0], 1, 0);
    // L1: 96(128) -> 192(256), relu
    gemm_mfma<<<dim3(NT, Opad[1] / 128), 256, 0, stream>>>(
        bufA, Wpad[1], bufB, Bp[1], Gp[1], BEp[1], RMp[1], RVp[1],
        Kpad[1], Cout[1], Opad[1], 1, 0);
    // L2: 192(256) -> 384, relu
    gemm_mfma<<<dim3(NT, Opad[2] / 128), 256, 0, stream>>>(
        bufB, Wpad[2], bufA, Bp[2], Gp[2], BEp[2], RMp[2], RVp[2],
        Kpad[2], Cout[2], Opad[2], 1, 0);
    // L3: 384 -> 768, relu
    gemm_mfma<<<dim3(NT, Opad[3] / 128), 256, 0, stream>>>(
        bufA, Wpad[3], bufB, Bp[3], Gp[3], BEp[3], RMp[3], RVp[3],
        Kpad[3], Cout[3], Opad[3], 1, 0);
    // L4: 768 -> 768, no act, fp32 out at offset B*H*W in (b,768,196) layout
    gemm_mfma<<<dim3(NT, Opad[4] / 128), 256, 0, stream>>>(
        bufB, Wpad[4], out + (size_t)NBATCH * HW, Bp[4], Gp[4], BEp[4], RMp[4], RVp[4],
        Kpad[4], Cout[4], 0, 0, 1);

    // output 0: sliced as float
    copy_sliced<<<(NBATCH * HW / 4) / 256, 256, 0, stream>>>((const int4*)sl,
                                                             (float4*)out);
}

// Round 4
// 417.787 us; speedup vs baseline: 3.1628x; 1.0586x over previous
//
#include <hip/hip_runtime.h>
#include <hip/hip_bf16.h>

// Problem constants
#define HW    50176            // 224*224
#define IMGW  224
#define SEG   196              // R*R
#define NBATCH 128
#define NCOL  (NBATCH * SEG)   // 25088 rows (pixels) of every GEMM
#define PB    14               // accumulation blocks per batch image
#define CHUNK (HW / PB)        // 3584 pixels per block
#define VCHUNK (CHUNK / 4)     // 896 float4 groups per block

typedef __attribute__((ext_vector_type(8))) short bf16x8;   // 8 bf16 = 4 VGPRs
typedef __attribute__((ext_vector_type(4))) float f32x4;
typedef unsigned long long u64;

static __device__ __forceinline__ ushort f2bf(float v) {
    __hip_bfloat16 h = __float2bfloat16(v);
    return *reinterpret_cast<ushort*>(&h);
}

// ---------------------------------------------------------------------------
// Kernel 1: segmented accumulation via packed u64 LDS atomics (4 per pixel).
// ---------------------------------------------------------------------------
__global__ __launch_bounds__(256) void seg_accum(const float* __restrict__ x,
                                                 const int*   __restrict__ sl,
                                                 float*       __restrict__ stats) {
    __shared__ u64 ls[4][SEG];
    int b    = blockIdx.x / PB;
    int part = blockIdx.x % PB;
    int tid  = threadIdx.x;

    for (int i = tid; i < 4 * SEG; i += 256) (&ls[0][0])[i] = 0ull;
    __syncthreads();

    const float* xb = x + (size_t)b * 3 * HW;
    const int*   sb = sl + (size_t)b * HW;
    int v0 = part * VCHUNK;

    for (int vi = tid; vi < VCHUNK; vi += 256) {
        int vg = v0 + vi;                 // float4 group index in image
        int4   id4 = ((const int4*)sb)[vg];
        float4 r4  = ((const float4*)xb)[vg];
        float4 g4  = ((const float4*)(xb + HW))[vg];
        float4 b4  = ((const float4*)(xb + 2 * HW))[vg];
        int p   = vg * 4;
        int row = p / IMGW;               // 4 | 224 -> all 4 pixels same row
        int col = p - row * IMGW;
        u64 rowbits = ((u64)1 << 48) | ((u64)(unsigned)row << 24);

#pragma unroll
        for (int q = 0; q < 4; ++q) {
            int   id = (q == 0) ? id4.x : (q == 1) ? id4.y : (q == 2) ? id4.z : id4.w;
            float r  = (q == 0) ? r4.x  : (q == 1) ? r4.y  : (q == 2) ? r4.z  : r4.w;
            float g  = (q == 0) ? g4.x  : (q == 1) ? g4.y  : (q == 2) ? g4.z  : g4.w;
            float bl = (q == 0) ? b4.x  : (q == 1) ? b4.y  : (q == 2) ? b4.z  : b4.w;

            unsigned qr  = (unsigned)fmaf(r,  8192.f, 131072.5f);   // (r+16)*8192
            unsigned qg  = (unsigned)fmaf(g,  8192.f, 131072.5f);
            unsigned qb  = (unsigned)fmaf(bl, 8192.f, 131072.5f);
            unsigned qr2 = (unsigned)fmaf(r * r,  2048.f, 0.5f);
            unsigned qg2 = (unsigned)fmaf(g * g,  2048.f, 0.5f);
            unsigned qb2 = (unsigned)fmaf(bl * bl, 2048.f, 0.5f);

            atomicAdd(&ls[0][id], rowbits | (unsigned)(col + q));
            atomicAdd(&ls[1][id], ((u64)qg  << 32) | qr);
            atomicAdd(&ls[2][id], ((u64)qr2 << 32) | qb);
            atomicAdd(&ls[3][id], ((u64)qb2 << 32) | qg2);
        }
    }
    __syncthreads();

    const float inv_s = 1.f / 8192.f, inv_q = 1.f / 2048.f;
    for (int i = tid; i < SEG; i += 256) {
        u64 v0p = ls[0][i];
        unsigned cnt = (unsigned)(v0p >> 48);
        if (!cnt) continue;
        float fc   = (float)cnt;
        float rows = (float)((unsigned)(v0p >> 24) & 0xFFFFFFu);
        float cols = (float)((unsigned)v0p & 0xFFFFFFu);
        u64 v1 = ls[1][i], v2 = ls[2][i], v3 = ls[3][i];
        float bias = 16.f * fc;
        float rsum = (float)(unsigned)v1         * inv_s - bias;
        float gsum = (float)(unsigned)(v1 >> 32) * inv_s - bias;
        float bsum = (float)(unsigned)v2         * inv_s - bias;
        float rsq  = (float)(unsigned)(v2 >> 32) * inv_q;
        float gsq  = (float)(unsigned)v3         * inv_q;
        float bsq  = (float)(unsigned)(v3 >> 32) * inv_q;

        size_t base = (size_t)b * SEG + i;
        atomicAdd(&stats[0 * NCOL + base], fc);
        atomicAdd(&stats[1 * NCOL + base], rows);
        atomicAdd(&stats[2 * NCOL + base], cols);
        atomicAdd(&stats[3 * NCOL + base], rsum);
        atomicAdd(&stats[4 * NCOL + base], gsum);
        atomicAdd(&stats[5 * NCOL + base], bsum);
        atomicAdd(&stats[6 * NCOL + base], rsq);
        atomicAdd(&stats[7 * NCOL + base], gsq);
        atomicAdd(&stats[8 * NCOL + base], bsq);
    }
}

// ---------------------------------------------------------------------------
// Kernel 2: 11 features -> bf16 F[n][64] (cols 11..63 zero). n = b*SEG+s.
// NOTE: F rows are stored k-group-swizzled (slot = kg ^ (n&7)) so gemm_mfma's
// swizzled staging reads see a plain row-major source after its own XOR.
// ---------------------------------------------------------------------------
__global__ __launch_bounds__(256) void feat_build(const float* __restrict__ x,
                                                  const float* __restrict__ stats,
                                                  ushort*      __restrict__ F) {
    int n = blockIdx.x * 256 + threadIdx.x;
    if (n >= NCOL) return;
    int b = n / SEG;

    float cnt  = stats[n];
    float safe = fmaxf(cnt, 1.f);
    float inv  = 1.f / safe;
    float mrow = stats[1 * NCOL + n] * inv;
    float mcol = stats[2 * NCOL + n] * inv;
    float mr   = stats[3 * NCOL + n] * inv;
    float mg   = stats[4 * NCOL + n] * inv;
    float mb   = stats[5 * NCOL + n] * inv;
    float den  = fmaxf(cnt - 1.f, 1.f);
    float vr = (stats[6 * NCOL + n] - cnt * mr * mr) / den;
    float vg = (stats[7 * NCOL + n] - cnt * mg * mg) / den;
    float vb = (stats[8 * NCOL + n] - cnt * mb * mb) / den;
    bool  has2 = cnt > 1.f;
    float sr = has2 ? sqrtf(fmaxf(vr, 0.f)) : 0.f;
    float sg = has2 ? sqrtf(fmaxf(vg, 0.f)) : 0.f;
    float sb = has2 ? sqrtf(fmaxf(vb, 0.f)) : 0.f;

    int ri = min(max((int)mrow, 0), IMGW - 1);
    int ci = min(max((int)mcol, 0), IMGW - 1);
    const float* xb = x + (size_t)b * 3 * HW;
    int pi = ri * IMGW + ci;
    float gr = xb[pi], gg = xb[HW + pi], gb = xb[2 * HW + pi];

    float mask = cnt > 0.f ? 1.f : 0.f;
    ushort* Fr = F + (size_t)n * 64;
#pragma unroll
    for (int k = 11; k < 64; ++k) Fr[k] = 0;
    Fr[0]  = f2bf(mrow * mask);
    Fr[1]  = f2bf(mcol * mask);
    Fr[2]  = f2bf(mr * mask);
    Fr[3]  = f2bf(mg * mask);
    Fr[4]  = f2bf(mb * mask);
    Fr[5]  = f2bf(sr * mask);
    Fr[6]  = f2bf(sg * mask);
    Fr[7]  = f2bf(sb * mask);
    Fr[8]  = f2bf(gr * mask);
    Fr[9]  = f2bf(gg * mask);
    Fr[10] = f2bf(gb * mask);
}

// ---------------------------------------------------------------------------
// Kernel 3: weight convert fp32 (Cout,K) -> bf16 padded (Opad,Kpad), zero pads
// ---------------------------------------------------------------------------
__global__ __launch_bounds__(256) void convert_w(const float* __restrict__ src,
                                                 ushort* __restrict__ dst,
                                                 int Cout, int K, int Kpad, int total) {
    int i = blockIdx.x * 256 + threadIdx.x;
    if (i >= total) return;
    int o = i / Kpad, k = i - o * Kpad;
    float v = (o < Cout && k < K) ? src[(size_t)o * K + k] : 0.f;
    dst[i] = f2bf(v);
}

// ---------------------------------------------------------------------------
// Kernel 4: bf16 MFMA GEMM + folded BN (+ReLU), XOR-swizzled LDS.
// C[n][o] = act(alpha[o] * sum_k Aact[n][k]*Wb[o][k] + beta[o])
// Block 128(n) x 128(o), BK=64, 4 waves in 2x2, 4x4 16x16x32 frags per wave.
// LDS layout: row r's 16B k-group g stored at slot g ^ (r&7).  Staging keeps
// global_load_lds' fixed lane->LDS mapping and applies the XOR to the SOURCE
// address; fragment reads XOR on the read side -> 2-way max bank aliasing.
// ---------------------------------------------------------------------------
__global__ __launch_bounds__(256) void gemm_mfma(const ushort* __restrict__ Aact,
                                                 const ushort* __restrict__ Wb,
                                                 void* __restrict__ outp,
                                                 const float* __restrict__ bias,
                                                 const float* __restrict__ gam,
                                                 const float* __restrict__ bet,
                                                 const float* __restrict__ rm,
                                                 const float* __restrict__ rv,
                                                 int Kpad, int Cout, int OutStride,
                                                 int act, int final_out) {
    __shared__ ushort As[128 * 64];   // [n][k-slot]
    __shared__ ushort Bs[128 * 64];   // [o][k-slot]

    int tid  = threadIdx.x;
    int lane = tid & 63;
    int wid  = tid >> 6;
    int wm   = wid & 1;               // wave row (n)
    int wn   = wid >> 1;              // wave col (o)
    int n0   = blockIdx.x * 128;
    int o0   = blockIdx.y * 128;
    int mrow = lane & 15;
    int quad = lane >> 4;
    int swz  = mrow & 7;              // row-dependent XOR for fragment reads

    f32x4 acc[4][4];
#pragma unroll
    for (int i = 0; i < 4; ++i)
#pragma unroll
        for (int j = 0; j < 4; ++j) acc[i][j] = (f32x4){0.f, 0.f, 0.f, 0.f};

    int ktiles = Kpad >> 6;
    for (int kt = 0; kt < ktiles; ++kt) {
        int kb = kt * 64;
        // stage A tile: 128 rows x 64 k, 16B per lane, 4 passes, swizzled source
#pragma unroll
        for (int p = 0; p < 4; ++p) {
            int flat = p * 256 + tid;
            int row = flat >> 3, kg = flat & 7;
            int kgs = kg ^ (row & 7);
            const ushort* gp = Aact + (size_t)(n0 + row) * Kpad + kb + kgs * 8;
            __builtin_amdgcn_global_load_lds(
                (const __attribute__((address_space(1))) void*)gp,
                (__attribute__((address_space(3))) void*)(As + (size_t)(p * 256 + wid * 64) * 8),
                16, 0, 0);
        }
        // stage B tile (weights), swizzled source
#pragma unroll
        for (int p = 0; p < 4; ++p) {
            int flat = p * 256 + tid;
            int row = flat >> 3, kg = flat & 7;
            int kgs = kg ^ (row & 7);
            const ushort* gp = Wb + (size_t)(o0 + row) * Kpad + kb + kgs * 8;
            __builtin_amdgcn_global_load_lds(
                (const __attribute__((address_space(1))) void*)gp,
                (__attribute__((address_space(3))) void*)(Bs + (size_t)(p * 256 + wid * 64) * 8),
                16, 0, 0);
        }
        __syncthreads();

#pragma unroll
        for (int ks = 0; ks < 2; ++ks) {
            bf16x8 af[4], bfr[4];
            int gbase = ks * 4 + quad;           // logical 16B group 0..7
            int slot  = (gbase ^ swz) * 8;       // swizzled element offset
#pragma unroll
            for (int i = 0; i < 4; ++i)
                af[i] = *(const bf16x8*)&As[(size_t)(wm * 64 + i * 16 + mrow) * 64 + slot];
#pragma unroll
            for (int j = 0; j < 4; ++j)
                bfr[j] = *(const bf16x8*)&Bs[(size_t)(wn * 64 + j * 16 + mrow) * 64 + slot];
#pragma unroll
            for (int i = 0; i < 4; ++i)
#pragma unroll
                for (int j = 0; j < 4; ++j)
                    acc[i][j] = __builtin_amdgcn_mfma_f32_16x16x32_bf16(af[i], bfr[j], acc[i][j], 0, 0, 0);
        }
        __syncthreads();
    }

    // epilogue: C row = n (quad*4+reg), col = o (lane&15)
#pragma unroll
    for (int j = 0; j < 4; ++j) {
        int o = o0 + wn * 64 + j * 16 + mrow;
        float al = 0.f, bt = 0.f;
        if (o < Cout) {
            float sc = gam[o] / sqrtf(rv[o] + 1e-5f);
            al = sc;
            bt = (bias[o] - rm[o]) * sc + bet[o];
        }
#pragma unroll
        for (int i = 0; i < 4; ++i) {
            int nbase = n0 + wm * 64 + i * 16 + quad * 4;
#pragma unroll
            for (int r = 0; r < 4; ++r) {
                float v = acc[i][j][r] * al + bt;
                if (act) v = fmaxf(v, 0.f);
                int n = nbase + r;
                if (final_out) {
                    int b = n / SEG, s = n - b * SEG;
                    ((float*)outp)[(size_t)b * 768 * SEG + (size_t)o * SEG + s] = v;
                } else {
                    ((ushort*)outp)[(size_t)n * OutStride + o] = f2bf(v);
                }
            }
        }
    }
}

// ---------------------------------------------------------------------------
// Kernel 5: copy sliced (int32) -> out as float values
// ---------------------------------------------------------------------------
__global__ __launch_bounds__(256) void copy_sliced(const int4* __restrict__ sl,
                                                   float4* __restrict__ out) {
    int i = blockIdx.x * 256 + threadIdx.x;
    int4 v = sl[i];
    out[i] = make_float4((float)v.x, (float)v.y, (float)v.z, (float)v.w);
}

// ---------------------------------------------------------------------------
extern "C" void kernel_launch(void* const* d_in, const int* in_sizes, int n_in,
                              void* d_out, int out_size, void* d_ws, size_t ws_size,
                              hipStream_t stream) {
    const float* x  = (const float*)d_in[0];
    const int*   sl = (const int*)d_in[1];
    const float* Wp[5], *Bp[5], *Gp[5], *BEp[5], *RMp[5], *RVp[5];
    for (int i = 0; i < 5; ++i) {
        Wp[i]  = (const float*)d_in[2 + 6 * i + 0];
        Bp[i]  = (const float*)d_in[2 + 6 * i + 1];
        Gp[i]  = (const float*)d_in[2 + 6 * i + 2];
        BEp[i] = (const float*)d_in[2 + 6 * i + 3];
        RMp[i] = (const float*)d_in[2 + 6 * i + 4];
        RVp[i] = (const float*)d_in[2 + 6 * i + 5];
    }
    float* out = (float*)d_out;

    // layer geometry: Kpad (=prev Opad), Kreal, Cout, Opad
    const int Kpad[5]  = {64, 128, 256, 384, 768};
    const int Kreal[5] = {11, 96, 192, 384, 768};
    const int Cout[5]  = {96, 192, 384, 768, 768};
    const int Opad[5]  = {128, 256, 384, 768, 768};

    // workspace layout
    char* wsb = (char*)d_ws;
    float*  stats = (float*)wsb;                        // 9*NCOL fp32
    wsb += (size_t)9 * NCOL * sizeof(float);
    ushort* F = (ushort*)wsb;                           // NCOL x 64 bf16
    wsb += (size_t)NCOL * 64 * sizeof(ushort);
    ushort* Wpad[5];
    for (int i = 0; i < 5; ++i) {
        Wpad[i] = (ushort*)wsb;
        wsb += (size_t)Opad[i] * Kpad[i] * sizeof(ushort);
    }
    ushort* bufA = (ushort*)wsb;                        // NCOL x 384 bf16 max
    wsb += (size_t)NCOL * 384 * sizeof(ushort);
    ushort* bufB = (ushort*)wsb;                        // NCOL x 768 bf16

    hipMemsetAsync(stats, 0, (size_t)9 * NCOL * sizeof(float), stream);

    for (int i = 0; i < 5; ++i) {
        int total = Opad[i] * Kpad[i];
        convert_w<<<(total + 255) / 256, 256, 0, stream>>>(
            Wp[i], Wpad[i], Cout[i], Kreal[i], Kpad[i], total);
    }

    seg_accum<<<NBATCH * PB, 256, 0, stream>>>(x, sl, stats);
    feat_build<<<(NCOL + 255) / 256, 256, 0, stream>>>(x, stats, F);

    const int NT = NCOL / 128;  // 196 row tiles
    // L0: 11(64) -> 96(128), relu
    gemm_mfma<<<dim3(NT, Opad[0] / 128), 256, 0, stream>>>(
        F, Wpad[0], bufA, Bp[0], Gp[0], BEp[0], RMp[0], RVp[0],
        Kpad[0], Cout[0], Opad[0], 1, 0);
    // L1: 96(128) -> 192(256), relu
    gemm_mfma<<<dim3(NT, Opad[1] / 128), 256, 0, stream>>>(
        bufA, Wpad[1], bufB, Bp[1], Gp[1], BEp[1], RMp[1], RVp[1],
        Kpad[1], Cout[1], Opad[1], 1, 0);
    // L2: 192(256) -> 384, relu
    gemm_mfma<<<dim3(NT, Opad[2] / 128), 256, 0, stream>>>(
        bufB, Wpad[2], bufA, Bp[2], Gp[2], BEp[2], RMp[2], RVp[2],
        Kpad[2], Cout[2], Opad[2], 1, 0);
    // L3: 384 -> 768, relu
    gemm_mfma<<<dim3(NT, Opad[3] / 128), 256, 0, stream>>>(
        bufA, Wpad[3], bufB, Bp[3], Gp[3], BEp[3], RMp[3], RVp[3],
        Kpad[3], Cout[3], Opad[3], 1, 0);
    // L4: 768 -> 768, no act, fp32 out at offset B*H*W in (b,768,196) layout
    gemm_mfma<<<dim3(NT, Opad[4] / 128), 256, 0, stream>>>(
        bufB, Wpad[4], out + (size_t)NBATCH * HW, Bp[4], Gp[4], BEp[4], RMp[4], RVp[4],
        Kpad[4], Cout[4], 0, 0, 1);

    // output 0: sliced as float
    copy_sliced<<<(NBATCH * HW / 4) / 256, 256, 0, stream>>>((const int4*)sl,
                                                             (float4*)out);
}